// Round 2
// baseline (597.684 us; speedup 1.0000x reference)
//
#include <hip/hip_runtime.h>
#include <hip/hip_bf16.h>

#define BATCH 16
#define SEQ   2048
#define DIM   128
#define PITCH 72   // ushorts per LDS row: 64 data + 8 pad -> rows 16B-aligned, 2-way-max (free) b128 reads
#define SCALE 0.08838834764831845f  // 1/sqrt(128)

typedef __attribute__((ext_vector_type(8))) short short8;
typedef __attribute__((ext_vector_type(4))) float f32x4;

__device__ __forceinline__ unsigned short f2bf(float x) {
    unsigned int u = __float_as_uint(x);
    u += 0x7fffu + ((u >> 16) & 1u);   // round-to-nearest-even
    return (unsigned short)(u >> 16);
}
__device__ __forceinline__ float bf2f(unsigned short h) {
    return __uint_as_float(((unsigned int)h) << 16);
}
__device__ __forceinline__ void cvt_hl(float x, unsigned short& h, unsigned short& l) {
    h = f2bf(x);
    l = f2bf(x - bf2f(h));             // residual: together ~17 mantissa bits
}

// ---------------------------------------------------------------------------
// Prep: one-time fp32 -> (bf16 hi, bf16 lo) conversion into MFMA-fragment-major
// layouts. Q/K: [b][rt(128)][kc(4)][hl(2)][lane(64)][e(8)]  (A/B over K rows).
// V (transposed for PV B-operand): [b][kc(64)][dt(8)][hl(2)][lane(64)][e(8)].
// Also zeroes lsum (replaces the separate memset dispatch).
// ---------------------------------------------------------------------------
__global__ __launch_bounds__(256) void prep_kernel(
    const float* __restrict__ Q, const float* __restrict__ Km, const float* __restrict__ V,
    unsigned short* __restrict__ Qf, unsigned short* __restrict__ Kf,
    unsigned short* __restrict__ Vf, float* __restrict__ lsum)
{
    const int bid = blockIdx.x, t = threadIdx.x;
    if (bid < 128) lsum[bid * 256 + t] = 0.f;   // 16*2048 floats zeroed
    if (bid < 4096) {
        const float* src = (bid < 2048) ? Q : Km;
        unsigned short* dst = (bid < 2048) ? Qf : Kf;
        int gid  = (bid & 2047) * 256 + t;      // [0, 524288)
        int lane = gid & 63;
        int kc   = (gid >> 6) & 3;
        int rt   = (gid >> 8) & 127;
        int b    = gid >> 15;
        int row  = rt * 16 + (lane & 15);
        int col  = kc * 32 + (lane >> 4) * 8;
        const float* p = src + ((size_t)b * SEQ + row) * DIM + col;
        float4 f0 = *(const float4*)p;
        float4 f1 = *(const float4*)(p + 4);
        float f[8] = {f0.x, f0.y, f0.z, f0.w, f1.x, f1.y, f1.z, f1.w};
        short8 H, L;
#pragma unroll
        for (int e = 0; e < 8; ++e) {
            unsigned short h, l;
            cvt_hl(f[e], h, l);
            H[e] = (short)h; L[e] = (short)l;
        }
        size_t o = ((size_t)((b * 128 + rt) * 4 + kc) * 2) * 512 + lane * 8;
        *(short8*)&dst[o]       = H;   // hi plane
        *(short8*)&dst[o + 512] = L;   // lo plane
    } else {
        int gid  = (bid - 4096) * 256 + t;      // [0, 524288)
        int lane = gid & 63;
        int dt   = (gid >> 6) & 7;
        int kc   = (gid >> 9) & 63;
        int b    = gid >> 15;
        int d    = dt * 16 + (lane & 15);
        int k0   = kc * 32 + (lane >> 4) * 8;
        const float* p = V + ((size_t)b * SEQ + k0) * DIM + d;
        short8 H, L;
#pragma unroll
        for (int e = 0; e < 8; ++e) {
            float x = p[(size_t)e * DIM];
            unsigned short h, l;
            cvt_hl(x, h, l);
            H[e] = (short)h; L[e] = (short)l;
        }
        size_t o = ((size_t)((b * 64 + kc) * 8 + dt) * 2) * 512 + lane * 8;
        *(short8*)&Vf[o]       = H;
        *(short8*)&Vf[o + 512] = L;
    }
}

// ---------------------------------------------------------------------------
// Kernel 1: E[b,q,k] = exp(scale * Q.K^T) (unnormalized) + row sums (atomic).
// LDS-FREE, BARRIER-FREE: fragments loaded directly from fragment-major Qf/Kf
// (coalesced 1KB dwordx4 per wave-load, L2-resident via XCD batch swizzle).
// Grid 4096 linear -> (kt,qt,b) with 2 batches pinned per XCD.
// 128x128 tile, 4 waves 2x2, each 64x64 via 4x4 of 16x16x32 MFMAs, 3-term.
// ---------------------------------------------------------------------------
__global__ __launch_bounds__(256, 2) void attn_scores_kernel(
    const unsigned short* __restrict__ Qf, const unsigned short* __restrict__ Kf,
    float* __restrict__ E, float* __restrict__ lsum)
{
    const int Lb = blockIdx.x;
    const int w  = (Lb & 7) * 512 + (Lb >> 3);   // XCD swizzle: 512 blocks (2 batches) per XCD
    const int b  = w >> 8, rem = w & 255;
    const int qt = rem >> 4, kt = rem & 15;
    const int t = threadIdx.x;
    const int lane = t & 63, wave = t >> 6;
    const int quad = lane >> 4, l15 = lane & 15;
    const int wr = wave >> 1, wc = wave & 1;

    f32x4 acc[4][4];
#pragma unroll
    for (int i = 0; i < 4; ++i)
#pragma unroll
        for (int j = 0; j < 4; ++j)
            acc[i][j] = (f32x4){0.f, 0.f, 0.f, 0.f};

    // rt stride = 4 kc * 2 hl * 512 = 4096 ushorts; kc stride = 1024; hl = 512
    const unsigned short* Qb = Qf + (size_t)(b * 128 + qt * 8 + wr * 4) * 4096 + lane * 8;
    const unsigned short* Kb = Kf + (size_t)(b * 128 + kt * 8 + wc * 4) * 4096 + lane * 8;

#pragma unroll
    for (int kk = 0; kk < 4; ++kk) {
        short8 ah[4], al[4], bh[4], bl[4];
#pragma unroll
        for (int i = 0; i < 4; ++i) {
            const unsigned short* pa = Qb + i * 4096 + kk * 1024;
            ah[i] = *(const short8*)pa;
            al[i] = *(const short8*)(pa + 512);
            const unsigned short* pb = Kb + i * 4096 + kk * 1024;
            bh[i] = *(const short8*)pb;
            bl[i] = *(const short8*)(pb + 512);
        }
#pragma unroll
        for (int i = 0; i < 4; ++i)
#pragma unroll
            for (int j = 0; j < 4; ++j) {
                acc[i][j] = __builtin_amdgcn_mfma_f32_16x16x32_bf16(ah[i], bh[j], acc[i][j], 0, 0, 0);
                acc[i][j] = __builtin_amdgcn_mfma_f32_16x16x32_bf16(ah[i], bl[j], acc[i][j], 0, 0, 0);
                acc[i][j] = __builtin_amdgcn_mfma_f32_16x16x32_bf16(al[i], bh[j], acc[i][j], 0, 0, 0);
            }
    }

    // epilogue: E = exp(scale * s), row-sum -> atomic into lsum
    float* Eb = E + ((size_t)b * SEQ + (size_t)qt * 128 + wr * 64) * SEQ
                  + (size_t)kt * 128 + wc * 64;
    float* Lsb = lsum + b * SEQ + qt * 128 + wr * 64;
#pragma unroll
    for (int i = 0; i < 4; ++i) {
        float rs0 = 0.f, rs1 = 0.f, rs2 = 0.f, rs3 = 0.f;
#pragma unroll
        for (int j = 0; j < 4; ++j) {
            f32x4 a = acc[i][j];
            float p0 = __expf(a[0] * SCALE);
            float p1 = __expf(a[1] * SCALE);
            float p2 = __expf(a[2] * SCALE);
            float p3 = __expf(a[3] * SCALE);
            size_t rb = (size_t)(i * 16 + quad * 4) * SEQ + j * 16 + l15;
            Eb[rb]           = p0;
            Eb[rb + SEQ]     = p1;
            Eb[rb + 2 * SEQ] = p2;
            Eb[rb + 3 * SEQ] = p3;
            rs0 += p0; rs1 += p1; rs2 += p2; rs3 += p3;
        }
        rs0 += __shfl_xor(rs0, 1); rs0 += __shfl_xor(rs0, 2);
        rs0 += __shfl_xor(rs0, 4); rs0 += __shfl_xor(rs0, 8);
        rs1 += __shfl_xor(rs1, 1); rs1 += __shfl_xor(rs1, 2);
        rs1 += __shfl_xor(rs1, 4); rs1 += __shfl_xor(rs1, 8);
        rs2 += __shfl_xor(rs2, 1); rs2 += __shfl_xor(rs2, 2);
        rs2 += __shfl_xor(rs2, 4); rs2 += __shfl_xor(rs2, 8);
        rs3 += __shfl_xor(rs3, 1); rs3 += __shfl_xor(rs3, 2);
        rs3 += __shfl_xor(rs3, 4); rs3 += __shfl_xor(rs3, 8);
        if (l15 == 0) {
            atomicAdd(&Lsb[i * 16 + quad * 4 + 0], rs0);
            atomicAdd(&Lsb[i * 16 + quad * 4 + 1], rs1);
            atomicAdd(&Lsb[i * 16 + quad * 4 + 2], rs2);
            atomicAdd(&Lsb[i * 16 + quad * 4 + 3], rs3);
        }
    }
}

// ---------------------------------------------------------------------------
// Kernel 2: normalize E in place (final weights) + out = P @ V (fused).
// RESTRUCTURED for occupancy: 32-row q-tiles -> 1024 blocks (4/CU), 512 thr,
// 8 waves each 16q x 32d (acc[2]), LDS 9.3KB, VGPR pinned <=64 via
// __launch_bounds__(512,8) -> 32 waves/CU target. Doubles the number of
// independent E read/write streams (BW was 2.2 TB/s at 40% occupancy).
// V fragments direct from Vf (L2/LLC-hot). E for kt+1 prefetched into regs.
// ---------------------------------------------------------------------------
__global__ __launch_bounds__(512, 8) void attn_out_kernel(
    const unsigned short* __restrict__ Vf, float* __restrict__ E,
    const float* __restrict__ lsum, float* __restrict__ O)
{
    __shared__ unsigned short sPh[32 * PITCH];
    __shared__ unsigned short sPl[32 * PITCH];
    __shared__ float sRl[32];

    const int Lb = blockIdx.x;
    const int w  = (Lb & 7) * 128 + (Lb >> 3);   // 128 blocks (2 batches) per XCD
    const int b  = w >> 6, qt = w & 63;          // qt: 64 tiles of 32 q-rows
    const int t = threadIdx.x;
    const int lane = t & 63, wave = t >> 6;
    const int quad = lane >> 4, l15 = lane & 15;
    const int wr = wave >> 2, wc = wave & 3;     // wr 0..1 (q 16-rows), wc 0..3 (d 32-cols)

    if (t < 32) sRl[t] = 1.0f / lsum[b * SEQ + qt * 32 + t];

    f32x4 acc[2];
#pragma unroll
    for (int j = 0; j < 2; ++j)
        acc[j] = (f32x4){0.f, 0.f, 0.f, 0.f};

    float* Ebase = E + ((size_t)b * SEQ + (size_t)qt * 32) * SEQ;
    // Vf: b stride 524288; kc stride 8192; dt stride 1024; hl 512
    const unsigned short* Vb = Vf + (size_t)b * 524288 + (size_t)(wc * 2) * 1024 + lane * 8;

    const int r0 = t >> 4;     // staging row 0..31
    const int c4 = t & 15;

    float4 e4 = *(const float4*)(Ebase + (size_t)r0 * SEQ + c4 * 4);

#pragma unroll 1
    for (int kt = 0; kt < 32; ++kt) {
        __syncthreads();       // prev compute done (LDS reusable); sRl visible on kt==0
        {
            float4 v = e4;
            float rl = sRl[r0];
            v.x *= rl; v.y *= rl; v.z *= rl; v.w *= rl;
            *(float4*)(Ebase + (size_t)r0 * SEQ + kt * 64 + c4 * 4) = v;  // final weights
            ushort4 H, Lo;
            cvt_hl(v.x, H.x, Lo.x); cvt_hl(v.y, H.y, Lo.y);
            cvt_hl(v.z, H.z, Lo.z); cvt_hl(v.w, H.w, Lo.w);
            int lofs = r0 * PITCH + c4 * 4;
            *(ushort4*)&sPh[lofs] = H;
            *(ushort4*)&sPl[lofs] = Lo;
        }
        __syncthreads();
        if (kt + 1 < 32) {     // prefetch next kt's E; hides HBM latency under MFMAs
            e4 = *(const float4*)(Ebase + (size_t)r0 * SEQ + (size_t)(kt + 1) * 64 + c4 * 4);
        }
#pragma unroll
        for (int kk = 0; kk < 2; ++kk) {
            int aoff = (wr * 16 + l15) * PITCH + kk * 32 + quad * 8;
            short8 ah = *(const short8*)&sPh[aoff];
            short8 al = *(const short8*)&sPl[aoff];
            const unsigned short* vp = Vb + (size_t)(kt * 2 + kk) * 8192;
#pragma unroll
            for (int j = 0; j < 2; ++j) {
                const unsigned short* pv = vp + j * 1024;
                short8 bh = *(const short8*)pv;
                short8 bl = *(const short8*)(pv + 512);
                acc[j] = __builtin_amdgcn_mfma_f32_16x16x32_bf16(ah, bh, acc[j], 0, 0, 0);
                acc[j] = __builtin_amdgcn_mfma_f32_16x16x32_bf16(ah, bl, acc[j], 0, 0, 0);
                acc[j] = __builtin_amdgcn_mfma_f32_16x16x32_bf16(al, bh, acc[j], 0, 0, 0);
            }
        }
    }

    float* Ob = O + ((size_t)b * SEQ + qt * 32 + wr * 16) * DIM + wc * 32;
#pragma unroll
    for (int j = 0; j < 2; ++j)
#pragma unroll
        for (int r = 0; r < 4; ++r)
            Ob[(quad * 4 + r) * DIM + j * 16 + l15] = acc[j][r];
}

extern "C" void kernel_launch(void* const* d_in, const int* in_sizes, int n_in,
                              void* d_out, int out_size, void* d_ws, size_t ws_size,
                              hipStream_t stream) {
    const float* Q = (const float*)d_in[0];
    const float* K = (const float*)d_in[1];
    const float* V = (const float*)d_in[2];
    float* out  = (float*)d_out;
    float* attn = out + (size_t)BATCH * SEQ * DIM;   // outputs concatenated: (out, attn_weights)

    // workspace layout: Qf (16MB) | Kf (16MB) | Vf (16MB) | lsum (128KB)
    unsigned short* Qf = (unsigned short*)d_ws;
    unsigned short* Kf = Qf + (size_t)8388608;
    unsigned short* Vf = Kf + (size_t)8388608;
    float* lsum = (float*)(Vf + (size_t)8388608);

    prep_kernel<<<6144, 256, 0, stream>>>(Q, K, V, Qf, Kf, Vf, lsum);
    attn_scores_kernel<<<4096, 256, 0, stream>>>(Qf, Kf, attn, lsum);
    attn_out_kernel<<<1024, 512, 0, stream>>>(Vf, attn, lsum, out);
}

// Round 3
// 532.885 us; speedup vs baseline: 1.1216x; 1.1216x over previous
//
#include <hip/hip_runtime.h>
#include <hip/hip_bf16.h>

#define BATCH 16
#define SEQ   2048
#define DIM   128
#define PITCH 72   // ushorts per LDS row: 64 data + 8 pad -> rows 16B-aligned, 2-way-max (free) b128 reads
#define SCALE 0.08838834764831845f  // 1/sqrt(128)

typedef __attribute__((ext_vector_type(8))) short short8;
typedef __attribute__((ext_vector_type(4))) float f32x4;

__device__ __forceinline__ unsigned short f2bf(float x) {
    unsigned int u = __float_as_uint(x);
    u += 0x7fffu + ((u >> 16) & 1u);   // round-to-nearest-even
    return (unsigned short)(u >> 16);
}
__device__ __forceinline__ float bf2f(unsigned short h) {
    return __uint_as_float(((unsigned int)h) << 16);
}
__device__ __forceinline__ void cvt_hl(float x, unsigned short& h, unsigned short& l) {
    h = f2bf(x);
    l = f2bf(x - bf2f(h));             // residual: together ~17 mantissa bits
}

// ---------------------------------------------------------------------------
// Prep: one-time fp32 -> (bf16 hi, bf16 lo) conversion into MFMA-fragment-major
// layouts. Q/K: [b][rt(128)][kc(4)][hl(2)][lane(64)][e(8)]  (A/B over K rows).
// V (transposed for PV B-operand): [b][kc(64)][dt(8)][hl(2)][lane(64)][e(8)].
// Also zeroes lsum (replaces the separate memset dispatch).
// ---------------------------------------------------------------------------
__global__ __launch_bounds__(256) void prep_kernel(
    const float* __restrict__ Q, const float* __restrict__ Km, const float* __restrict__ V,
    unsigned short* __restrict__ Qf, unsigned short* __restrict__ Kf,
    unsigned short* __restrict__ Vf, float* __restrict__ lsum)
{
    const int bid = blockIdx.x, t = threadIdx.x;
    if (bid < 128) lsum[bid * 256 + t] = 0.f;   // 16*2048 floats zeroed
    if (bid < 4096) {
        const float* src = (bid < 2048) ? Q : Km;
        unsigned short* dst = (bid < 2048) ? Qf : Kf;
        int gid  = (bid & 2047) * 256 + t;      // [0, 524288)
        int lane = gid & 63;
        int kc   = (gid >> 6) & 3;
        int rt   = (gid >> 8) & 127;
        int b    = gid >> 15;
        int row  = rt * 16 + (lane & 15);
        int col  = kc * 32 + (lane >> 4) * 8;
        const float* p = src + ((size_t)b * SEQ + row) * DIM + col;
        float4 f0 = *(const float4*)p;
        float4 f1 = *(const float4*)(p + 4);
        float f[8] = {f0.x, f0.y, f0.z, f0.w, f1.x, f1.y, f1.z, f1.w};
        short8 H, L;
#pragma unroll
        for (int e = 0; e < 8; ++e) {
            unsigned short h, l;
            cvt_hl(f[e], h, l);
            H[e] = (short)h; L[e] = (short)l;
        }
        size_t o = ((size_t)((b * 128 + rt) * 4 + kc) * 2) * 512 + lane * 8;
        *(short8*)&dst[o]       = H;   // hi plane
        *(short8*)&dst[o + 512] = L;   // lo plane
    } else {
        int gid  = (bid - 4096) * 256 + t;      // [0, 524288)
        int lane = gid & 63;
        int dt   = (gid >> 6) & 7;
        int kc   = (gid >> 9) & 63;
        int b    = gid >> 15;
        int d    = dt * 16 + (lane & 15);
        int k0   = kc * 32 + (lane >> 4) * 8;
        const float* p = V + ((size_t)b * SEQ + k0) * DIM + d;
        short8 H, L;
#pragma unroll
        for (int e = 0; e < 8; ++e) {
            float x = p[(size_t)e * DIM];
            unsigned short h, l;
            cvt_hl(x, h, l);
            H[e] = (short)h; L[e] = (short)l;
        }
        size_t o = ((size_t)((b * 64 + kc) * 8 + dt) * 2) * 512 + lane * 8;
        *(short8*)&Vf[o]       = H;
        *(short8*)&Vf[o + 512] = L;
    }
}

// ---------------------------------------------------------------------------
// Kernel A: lsum[b,q] = sum_k exp(scale*Q.K^T)  — NO E write (E is recomputed
// in the fused kernel). Pure MFMA + exp + shfl-reduce + atomics.
// Grid 4096 linear -> (kt,qt,b), XCD swizzle, 128x128 tile, 4 waves 2x2.
// ---------------------------------------------------------------------------
__global__ __launch_bounds__(256, 2) void attn_lsum_kernel(
    const unsigned short* __restrict__ Qf, const unsigned short* __restrict__ Kf,
    float* __restrict__ lsum)
{
    const int Lb = blockIdx.x;
    const int w  = (Lb & 7) * 512 + (Lb >> 3);   // XCD swizzle: 512 blocks (2 batches) per XCD
    const int b  = w >> 8, rem = w & 255;
    const int qt = rem >> 4, kt = rem & 15;
    const int t = threadIdx.x;
    const int lane = t & 63, wave = t >> 6;
    const int quad = lane >> 4, l15 = lane & 15;
    const int wr = wave >> 1, wc = wave & 1;

    f32x4 acc[4][4];
#pragma unroll
    for (int i = 0; i < 4; ++i)
#pragma unroll
        for (int j = 0; j < 4; ++j)
            acc[i][j] = (f32x4){0.f, 0.f, 0.f, 0.f};

    const unsigned short* Qb = Qf + (size_t)(b * 128 + qt * 8 + wr * 4) * 4096 + lane * 8;
    const unsigned short* Kb = Kf + (size_t)(b * 128 + kt * 8 + wc * 4) * 4096 + lane * 8;

#pragma unroll
    for (int kk = 0; kk < 4; ++kk) {
        short8 ah[4], al[4], bh[4], bl[4];
#pragma unroll
        for (int i = 0; i < 4; ++i) {
            const unsigned short* pa = Qb + i * 4096 + kk * 1024;
            ah[i] = *(const short8*)pa;
            al[i] = *(const short8*)(pa + 512);
            const unsigned short* pb = Kb + i * 4096 + kk * 1024;
            bh[i] = *(const short8*)pb;
            bl[i] = *(const short8*)(pb + 512);
        }
#pragma unroll
        for (int i = 0; i < 4; ++i)
#pragma unroll
            for (int j = 0; j < 4; ++j) {
                acc[i][j] = __builtin_amdgcn_mfma_f32_16x16x32_bf16(ah[i], bh[j], acc[i][j], 0, 0, 0);
                acc[i][j] = __builtin_amdgcn_mfma_f32_16x16x32_bf16(ah[i], bl[j], acc[i][j], 0, 0, 0);
                acc[i][j] = __builtin_amdgcn_mfma_f32_16x16x32_bf16(al[i], bh[j], acc[i][j], 0, 0, 0);
            }
    }

    float* Lsb = lsum + b * SEQ + qt * 128 + wr * 64;
#pragma unroll
    for (int i = 0; i < 4; ++i) {
        float rs0 = 0.f, rs1 = 0.f, rs2 = 0.f, rs3 = 0.f;
#pragma unroll
        for (int j = 0; j < 4; ++j) {
            f32x4 a = acc[i][j];
            rs0 += __expf(a[0] * SCALE);
            rs1 += __expf(a[1] * SCALE);
            rs2 += __expf(a[2] * SCALE);
            rs3 += __expf(a[3] * SCALE);
        }
        rs0 += __shfl_xor(rs0, 1); rs0 += __shfl_xor(rs0, 2);
        rs0 += __shfl_xor(rs0, 4); rs0 += __shfl_xor(rs0, 8);
        rs1 += __shfl_xor(rs1, 1); rs1 += __shfl_xor(rs1, 2);
        rs1 += __shfl_xor(rs1, 4); rs1 += __shfl_xor(rs1, 8);
        rs2 += __shfl_xor(rs2, 1); rs2 += __shfl_xor(rs2, 2);
        rs2 += __shfl_xor(rs2, 4); rs2 += __shfl_xor(rs2, 8);
        rs3 += __shfl_xor(rs3, 1); rs3 += __shfl_xor(rs3, 2);
        rs3 += __shfl_xor(rs3, 4); rs3 += __shfl_xor(rs3, 8);
        if (l15 == 0) {
            atomicAdd(&Lsb[i * 16 + quad * 4 + 0], rs0);
            atomicAdd(&Lsb[i * 16 + quad * 4 + 1], rs1);
            atomicAdd(&Lsb[i * 16 + quad * 4 + 2], rs2);
            atomicAdd(&Lsb[i * 16 + quad * 4 + 3], rs3);
        }
    }
}

// ---------------------------------------------------------------------------
// Kernel B (fused): recompute QK^T, exp, x(1/l) -> write final attn weights
// (E written ONCE, never read) AND accumulate O = P @ V in registers.
// Grid 1024 linear -> (b, qt of 32 q-rows), XCD swizzle. 256 thr, 4 waves
// (wr x wc = 2x2): per wave QK^T 16q x 32k, PV 16q x 64d. Q fragments
// register-resident across the whole kt loop. P double-buffered in LDS ->
// ONE barrier per kt. E stores issued AFTER the barrier so they stay in
// flight under the PV MFMAs (drained at the next iteration's barrier).
// ---------------------------------------------------------------------------
__global__ __launch_bounds__(256, 4) void attn_fused_kernel(
    const unsigned short* __restrict__ Qf, const unsigned short* __restrict__ Kf,
    const unsigned short* __restrict__ Vf, const float* __restrict__ lsum,
    float* __restrict__ E, float* __restrict__ O)
{
    __shared__ unsigned short sPh[2][32 * PITCH];
    __shared__ unsigned short sPl[2][32 * PITCH];
    __shared__ float sRl[32];

    const int Lb = blockIdx.x;
    const int w  = (Lb & 7) * 128 + (Lb >> 3);   // 128 blocks (2 batches) per XCD
    const int b  = w >> 6, qt = w & 63;          // qt: 64 tiles of 32 q-rows
    const int t = threadIdx.x;
    const int lane = t & 63, wave = t >> 6;
    const int quad = lane >> 4, l15 = lane & 15;
    const int wr = wave >> 1, wc = wave & 1;     // wr: q 16-rows; wc: k-32 / d-64 split

    if (t < 32) sRl[t] = 1.0f / lsum[b * SEQ + qt * 32 + t];

    // Q fragments, register-resident: rt = qt*2 + wr
    short8 qh[4], ql[4];
    const unsigned short* Qb = Qf + (size_t)(b * 128 + qt * 2 + wr) * 4096 + lane * 8;
#pragma unroll
    for (int kc = 0; kc < 4; ++kc) {
        qh[kc] = *(const short8*)(Qb + kc * 1024);
        ql[kc] = *(const short8*)(Qb + kc * 1024 + 512);
    }

    f32x4 accO[4];
#pragma unroll
    for (int j = 0; j < 4; ++j)
        accO[j] = (f32x4){0.f, 0.f, 0.f, 0.f};

    __syncthreads();   // sRl ready
    float rlv[4];
#pragma unroll
    for (int r = 0; r < 4; ++r) rlv[r] = sRl[wr * 16 + quad * 4 + r];

    const unsigned short* Kb = Kf + (size_t)(b * 128) * 4096 + lane * 8;
    const unsigned short* Vb = Vf + (size_t)b * 524288 + (size_t)(wc * 4) * 1024 + lane * 8;
    float* Erow = E + ((size_t)b * SEQ + qt * 32 + wr * 16 + quad * 4) * SEQ + wc * 32 + l15;

    int buf = 0;
#pragma unroll 1
    for (int kt = 0; kt < 32; ++kt) {
        // ---- QK^T: P[16q x 32k] for this wave ----
        f32x4 accP[2];
        accP[0] = (f32x4){0.f, 0.f, 0.f, 0.f};
        accP[1] = (f32x4){0.f, 0.f, 0.f, 0.f};
#pragma unroll
        for (int kc = 0; kc < 4; ++kc) {
#pragma unroll
            for (int j = 0; j < 2; ++j) {
                const unsigned short* pk = Kb + (size_t)(kt * 4 + wc * 2 + j) * 4096 + kc * 1024;
                short8 kh = *(const short8*)pk;
                short8 kl = *(const short8*)(pk + 512);
                accP[j] = __builtin_amdgcn_mfma_f32_16x16x32_bf16(qh[kc], kh, accP[j], 0, 0, 0);
                accP[j] = __builtin_amdgcn_mfma_f32_16x16x32_bf16(qh[kc], kl, accP[j], 0, 0, 0);
                accP[j] = __builtin_amdgcn_mfma_f32_16x16x32_bf16(ql[kc], kh, accP[j], 0, 0, 0);
            }
        }
        // ---- exp, normalize, stage P to LDS (E stores deferred past barrier) ----
        float pv[2][4];
#pragma unroll
        for (int j = 0; j < 2; ++j)
#pragma unroll
            for (int r = 0; r < 4; ++r) {
                float p = __expf(accP[j][r] * SCALE) * rlv[r];
                pv[j][r] = p;
                unsigned short h, l;
                cvt_hl(p, h, l);
                int lofs = (wr * 16 + quad * 4 + r) * PITCH + wc * 32 + j * 16 + l15;
                sPh[buf][lofs] = h;
                sPl[buf][lofs] = l;
            }
        __syncthreads();
        // E stores: in flight under the PV MFMAs, drained at next iteration's barrier
#pragma unroll
        for (int j = 0; j < 2; ++j)
#pragma unroll
            for (int r = 0; r < 4; ++r)
                Erow[(size_t)r * SEQ + kt * 64 + j * 16] = pv[j][r];
        // ---- PV: accO += P @ V ----
#pragma unroll
        for (int kc = 0; kc < 2; ++kc) {
            int aoff = (wr * 16 + l15) * PITCH + kc * 32 + quad * 8;
            short8 ah = *(const short8*)&sPh[buf][aoff];
            short8 al = *(const short8*)&sPl[buf][aoff];
            const unsigned short* vp = Vb + (size_t)(kt * 2 + kc) * 8192;
#pragma unroll
            for (int j = 0; j < 4; ++j) {
                const unsigned short* pvf = vp + j * 1024;
                short8 bh = *(const short8*)pvf;
                short8 bl = *(const short8*)(pvf + 512);
                accO[j] = __builtin_amdgcn_mfma_f32_16x16x32_bf16(ah, bh, accO[j], 0, 0, 0);
                accO[j] = __builtin_amdgcn_mfma_f32_16x16x32_bf16(ah, bl, accO[j], 0, 0, 0);
                accO[j] = __builtin_amdgcn_mfma_f32_16x16x32_bf16(al, bh, accO[j], 0, 0, 0);
            }
        }
        buf ^= 1;
    }

    float* Ob = O + ((size_t)b * SEQ + qt * 32 + wr * 16 + quad * 4) * DIM + wc * 64 + l15;
#pragma unroll
    for (int j = 0; j < 4; ++j)
#pragma unroll
        for (int r = 0; r < 4; ++r)
            Ob[(size_t)r * DIM + j * 16] = accO[j][r];
}

extern "C" void kernel_launch(void* const* d_in, const int* in_sizes, int n_in,
                              void* d_out, int out_size, void* d_ws, size_t ws_size,
                              hipStream_t stream) {
    const float* Q = (const float*)d_in[0];
    const float* K = (const float*)d_in[1];
    const float* V = (const float*)d_in[2];
    float* out  = (float*)d_out;
    float* attn = out + (size_t)BATCH * SEQ * DIM;   // outputs concatenated: (out, attn_weights)

    // workspace layout: Qf (16MB) | Kf (16MB) | Vf (16MB) | lsum (128KB)
    unsigned short* Qf = (unsigned short*)d_ws;
    unsigned short* Kf = Qf + (size_t)8388608;
    unsigned short* Vf = Kf + (size_t)8388608;
    float* lsum = (float*)(Vf + (size_t)8388608);

    prep_kernel<<<6144, 256, 0, stream>>>(Q, K, V, Qf, Kf, Vf, lsum);
    attn_lsum_kernel<<<4096, 256, 0, stream>>>(Qf, Kf, lsum);
    attn_fused_kernel<<<1024, 256, 0, stream>>>(Qf, Kf, Vf, lsum, attn, out);
}